// Round 2
// baseline (67466.882 us; speedup 1.0000x reference)
//
#include <hip/hip_runtime.h>
#include <math.h>

// Problem constants
#define D_MODEL 1024
#define N_WIN   240
#define TOK     256
#define NH      16
#define DH      64
#define CHUNK   8       // windows per phase-1 chunk (keeps workspace ~56 MB)
#define NCHUNK  30      // 240 / 8

// ---------------------------------------------------------------------------
// Generic fp32 GEMM: C[m,n] = act(sum_k A[m,k]*W[n,k] + bias[n])
// A: [M,K] row-major, W: [N,K] row-major (i.e. C = A @ W^T + b)
// Block: 256 thr, tile 64x64, BK=16, 4x4 per thread.
// ---------------------------------------------------------------------------
__global__ __launch_bounds__(256) void gemm_bias_k(
    const float* __restrict__ A, const float* __restrict__ W,
    const float* __restrict__ bias, float* __restrict__ C,
    int M, int N, int K, int relu)
{
    __shared__ float As[16][68];
    __shared__ float Ws[16][68];
    const int tid = threadIdx.x;
    const int tx = tid & 15, ty = tid >> 4;
    const int m0 = blockIdx.y << 6, n0 = blockIdx.x << 6;
    float acc[4][4] = {};
    for (int k0 = 0; k0 < K; k0 += 16) {
#pragma unroll
        for (int i = 0; i < 4; ++i) {
            int idx = tid + (i << 8);
            int mm = idx >> 4, kk = idx & 15;
            As[kk][mm] = A[(size_t)(m0 + mm) * K + (k0 + kk)];
            Ws[kk][mm] = W[(size_t)(n0 + mm) * K + (k0 + kk)];
        }
        __syncthreads();
#pragma unroll
        for (int kk = 0; kk < 16; ++kk) {
            const float4 a4 = *(const float4*)&As[kk][ty << 2];
            const float4 w4 = *(const float4*)&Ws[kk][tx << 2];
            const float av[4] = {a4.x, a4.y, a4.z, a4.w};
            const float wv[4] = {w4.x, w4.y, w4.z, w4.w};
#pragma unroll
            for (int r = 0; r < 4; ++r)
#pragma unroll
                for (int c = 0; c < 4; ++c)
                    acc[r][c] = fmaf(av[r], wv[c], acc[r][c]);
        }
        __syncthreads();
    }
#pragma unroll
    for (int r = 0; r < 4; ++r) {
        float4 o;
        o.x = acc[r][0] + bias[n0 + (tx << 2) + 0];
        o.y = acc[r][1] + bias[n0 + (tx << 2) + 1];
        o.z = acc[r][2] + bias[n0 + (tx << 2) + 2];
        o.w = acc[r][3] + bias[n0 + (tx << 2) + 3];
        if (relu) {
            o.x = fmaxf(o.x, 0.f); o.y = fmaxf(o.y, 0.f);
            o.z = fmaxf(o.z, 0.f); o.w = fmaxf(o.w, 0.f);
        }
        *(float4*)&C[(size_t)(m0 + (ty << 2) + r) * N + n0 + (tx << 2)] = o;
    }
}

// ---------------------------------------------------------------------------
// Phase-1 QKV GEMM with window-gather fused into the A read.
// Logical A row m (within chunk) maps to path row (w0 + m/256)*16 + (m%256).
// M = CHUNK*256 = 2048, N = 3072, K = 1024.
// ---------------------------------------------------------------------------
__global__ __launch_bounds__(256) void gemm_win_qkv_k(
    const float* __restrict__ path, const float* __restrict__ W,
    const float* __restrict__ bias, float* __restrict__ C, int w0)
{
    const int N = 3 * D_MODEL, K = D_MODEL;
    __shared__ float As[16][68];
    __shared__ float Ws[16][68];
    const int tid = threadIdx.x;
    const int tx = tid & 15, ty = tid >> 4;
    const int m0 = blockIdx.y << 6, n0 = blockIdx.x << 6;
    float acc[4][4] = {};
    for (int k0 = 0; k0 < K; k0 += 16) {
#pragma unroll
        for (int i = 0; i < 4; ++i) {
            int idx = tid + (i << 8);
            int mm = idx >> 4, kk = idx & 15;
            int ml = m0 + mm;                       // logical row in chunk
            int prow = (w0 + (ml >> 8)) * 16 + (ml & 255);
            As[kk][mm] = path[(size_t)prow * K + (k0 + kk)];
            Ws[kk][mm] = W[(size_t)(n0 + mm) * K + (k0 + kk)];
        }
        __syncthreads();
#pragma unroll
        for (int kk = 0; kk < 16; ++kk) {
            const float4 a4 = *(const float4*)&As[kk][ty << 2];
            const float4 w4 = *(const float4*)&Ws[kk][tx << 2];
            const float av[4] = {a4.x, a4.y, a4.z, a4.w};
            const float wv[4] = {w4.x, w4.y, w4.z, w4.w};
#pragma unroll
            for (int r = 0; r < 4; ++r)
#pragma unroll
                for (int c = 0; c < 4; ++c)
                    acc[r][c] = fmaf(av[r], wv[c], acc[r][c]);
        }
        __syncthreads();
    }
#pragma unroll
    for (int r = 0; r < 4; ++r) {
        float4 o;
        o.x = acc[r][0] + bias[n0 + (tx << 2) + 0];
        o.y = acc[r][1] + bias[n0 + (tx << 2) + 1];
        o.z = acc[r][2] + bias[n0 + (tx << 2) + 2];
        o.w = acc[r][3] + bias[n0 + (tx << 2) + 3];
        *(float4*)&C[(size_t)(m0 + (ty << 2) + r) * N + n0 + (tx << 2)] = o;
    }
}

// ---------------------------------------------------------------------------
// Scan projection: one launch computes
//   Q  = X_i @ wq2^T  + bq2   (rows    0..1023 of w_in2)
//   KV = cum @ wkv2^T + bkv2  (rows 1024..3071 of w_in2)
// Grid (48, 4); block picks its A / output by column tile.
// ---------------------------------------------------------------------------
__global__ __launch_bounds__(256) void scan_proj_k(
    const float* __restrict__ Xi, const float* __restrict__ cum,
    const float* __restrict__ W, const float* __restrict__ bias,
    float* __restrict__ Qb, float* __restrict__ KVb)
{
    const int K = D_MODEL;
    __shared__ float As[16][68];
    __shared__ float Ws[16][68];
    const int tid = threadIdx.x;
    const int tx = tid & 15, ty = tid >> 4;
    const int m0 = blockIdx.y << 6, n0 = blockIdx.x << 6;
    const float* A;
    float* Cp;
    int ldc, nc;
    if (n0 < D_MODEL) { A = Xi;  Cp = Qb;  ldc = D_MODEL;     nc = n0; }
    else              { A = cum; Cp = KVb; ldc = 2 * D_MODEL; nc = n0 - D_MODEL; }
    float acc[4][4] = {};
    for (int k0 = 0; k0 < K; k0 += 16) {
#pragma unroll
        for (int i = 0; i < 4; ++i) {
            int idx = tid + (i << 8);
            int mm = idx >> 4, kk = idx & 15;
            As[kk][mm] = A[(size_t)(m0 + mm) * K + (k0 + kk)];
            Ws[kk][mm] = W[(size_t)(n0 + mm) * K + (k0 + kk)];
        }
        __syncthreads();
#pragma unroll
        for (int kk = 0; kk < 16; ++kk) {
            const float4 a4 = *(const float4*)&As[kk][ty << 2];
            const float4 w4 = *(const float4*)&Ws[kk][tx << 2];
            const float av[4] = {a4.x, a4.y, a4.z, a4.w};
            const float wv[4] = {w4.x, w4.y, w4.z, w4.w};
#pragma unroll
            for (int r = 0; r < 4; ++r)
#pragma unroll
                for (int c = 0; c < 4; ++c)
                    acc[r][c] = fmaf(av[r], wv[c], acc[r][c]);
        }
        __syncthreads();
    }
#pragma unroll
    for (int r = 0; r < 4; ++r) {
        float4 o;
        o.x = acc[r][0] + bias[n0 + (tx << 2) + 0];
        o.y = acc[r][1] + bias[n0 + (tx << 2) + 1];
        o.z = acc[r][2] + bias[n0 + (tx << 2) + 2];
        o.w = acc[r][3] + bias[n0 + (tx << 2) + 3];
        *(float4*)&Cp[(size_t)(m0 + (ty << 2) + r) * ldc + nc + (tx << 2)] = o;
    }
}

// ---------------------------------------------------------------------------
// Multi-head attention core (L=256 keys, Dh=64), online softmax.
// Grid: (row_slice 0..3, head 0..NH-1, batch). Block 256 = 64 rows x 4 waves;
// wave s handles key slice j in [s*64, s*64+64) -> LDS merge of (m,l,O).
// ---------------------------------------------------------------------------
__global__ __launch_bounds__(256) void attn_k(
    const float* __restrict__ Q, const float* __restrict__ Kp,
    const float* __restrict__ Vp, float* __restrict__ O,
    int ldq, int ldk, int ldo,
    long long qBatch, long long kBatch, long long oBatch, float scale)
{
    const int h = blockIdx.y;
    const long long b = blockIdx.z;
    const float* qb = Q  + b * qBatch + h * DH;
    const float* kb = Kp + b * kBatch + h * DH;
    const float* vb = Vp + b * kBatch + h * DH;
    const int tid = threadIdx.x;
    const int rr = tid & 63;         // row within slice block
    const int s  = tid >> 6;         // key slice (== wave id)
    const int r  = (blockIdx.x << 6) + rr;

    float4 qr[16];
    const float* qrow = qb + (size_t)r * ldq;
#pragma unroll
    for (int i = 0; i < 16; ++i) qr[i] = *(const float4*)(qrow + i * 4);

    float m = -INFINITY, l = 0.f;
    float4 o[16];
#pragma unroll
    for (int i = 0; i < 16; ++i) o[i] = make_float4(0.f, 0.f, 0.f, 0.f);

    const int j0 = s << 6;
    for (int j = j0; j < j0 + 64; ++j) {
        const float* krow = kb + (size_t)j * ldk;
        const float* vrow = vb + (size_t)j * ldk;
        float dot = 0.f;
#pragma unroll
        for (int i = 0; i < 16; ++i) {
            float4 k4 = *(const float4*)(krow + i * 4);
            dot = fmaf(qr[i].x, k4.x, dot);
            dot = fmaf(qr[i].y, k4.y, dot);
            dot = fmaf(qr[i].z, k4.z, dot);
            dot = fmaf(qr[i].w, k4.w, dot);
        }
        float sc = dot * scale;
        float mn = fmaxf(m, sc);
        float alpha = __expf(m - mn);   // exp(-inf)=0 on first iter
        float p = __expf(sc - mn);
        l = l * alpha + p;
        m = mn;
#pragma unroll
        for (int i = 0; i < 16; ++i) {
            float4 v4 = *(const float4*)(vrow + i * 4);
            o[i].x = fmaf(p, v4.x, o[i].x * alpha);
            o[i].y = fmaf(p, v4.y, o[i].y * alpha);
            o[i].z = fmaf(p, v4.z, o[i].z * alpha);
            o[i].w = fmaf(p, v4.w, o[i].w * alpha);
        }
    }

    // merge 4 slices
    __shared__ float sm[4][64];
    __shared__ float sl[4][64];
    __shared__ float Oa[64][68];
    sm[s][rr] = m;
    sl[s][rr] = l;
    __syncthreads();
    float M2 = fmaxf(fmaxf(sm[0][rr], sm[1][rr]), fmaxf(sm[2][rr], sm[3][rr]));
    float L = 0.f;
#pragma unroll
    for (int s2 = 0; s2 < 4; ++s2) L += sl[s2][rr] * __expf(sm[s2][rr] - M2);
    float myw = __expf(m - M2);
#pragma unroll
    for (int i = 0; i < 16; ++i) {
        o[i].x *= myw; o[i].y *= myw; o[i].z *= myw; o[i].w *= myw;
    }
#pragma unroll
    for (int p = 0; p < 4; ++p) {
        if (s == p) {
            if (p == 0) {
#pragma unroll
                for (int i = 0; i < 16; ++i)
                    *(float4*)&Oa[rr][i << 2] = o[i];
            } else {
#pragma unroll
                for (int i = 0; i < 16; ++i) {
                    Oa[rr][(i << 2) + 0] += o[i].x;
                    Oa[rr][(i << 2) + 1] += o[i].y;
                    Oa[rr][(i << 2) + 2] += o[i].z;
                    Oa[rr][(i << 2) + 3] += o[i].w;
                }
            }
        }
        __syncthreads();
    }
    float invL = 1.f / L;
    float* orow = O + b * oBatch + h * DH + (size_t)r * ldo;
#pragma unroll
    for (int i = 0; i < 4; ++i) {
        int d = (s << 4) + (i << 2);
        float4 res;
        res.x = Oa[rr][d + 0] * invL;
        res.y = Oa[rr][d + 1] * invL;
        res.z = Oa[rr][d + 2] * invL;
        res.w = Oa[rr][d + 3] * invL;
        *(float4*)(orow + d) = res;
    }
}

// ---------------------------------------------------------------------------
extern "C" void kernel_launch(void* const* d_in, const int* in_sizes, int n_in,
                              void* d_out, int out_size, void* d_ws, size_t ws_size,
                              hipStream_t stream)
{
    const float* path   = (const float*)d_in[0];
    const float* w_in1  = (const float*)d_in[1];
    const float* b_in1  = (const float*)d_in[2];
    const float* w_out1 = (const float*)d_in[3];
    const float* b_out1 = (const float*)d_in[4];
    const float* w_lin  = (const float*)d_in[5];
    const float* b_lin  = (const float*)d_in[6];
    const float* w_in2  = (const float*)d_in[7];
    const float* b_in2  = (const float*)d_in[8];
    const float* w_out2 = (const float*)d_in[9];
    const float* b_out2 = (const float*)d_in[10];
    float* out = (float*)d_out;

    // workspace layout (floats) — total ~13.9M floats = 55.6 MB
    float* ws = (float*)d_ws;
    const size_t WIN_ELEMS = (size_t)TOK * D_MODEL;          // 262144
    float* qkv    = ws;                                      // CHUNK*256*3072
    float* ao     = qkv + (size_t)CHUNK * TOK * 3 * D_MODEL; // CHUNK*262144
    float* ybuf   = ao + (size_t)CHUNK * WIN_ELEMS;          // CHUNK*262144
    float* Xchunk = ybuf + (size_t)CHUNK * WIN_ELEMS;        // CHUNK*262144
    float* Qb     = Xchunk + (size_t)CHUNK * WIN_ELEMS;      // 262144
    float* KVb    = Qb + WIN_ELEMS;                          // 524288
    float* AO2    = KVb + 2 * WIN_ELEMS;                     // 262144
    float* cum    = AO2 + WIN_ELEMS;                         // 262144

    const float scale = 0.125f;   // 1/sqrt(64)
    const int Mc = CHUNK * TOK;   // 2048 rows per chunk

    // Interleaved: compute one chunk of phase-1 window outputs, then run
    // that chunk's scan steps (single stream => strict ordering, and the
    // chunk buffer is only overwritten after its scan steps consumed it).
    for (int c = 0; c < NCHUNK; ++c) {
        int w0 = c * CHUNK;
        // ---- Phase 1 for windows [w0, w0+CHUNK) ----
        gemm_win_qkv_k<<<dim3(48, Mc / 64), 256, 0, stream>>>(
            path, w_in1, b_in1, qkv, w0);
        attn_k<<<dim3(4, NH, CHUNK), 256, 0, stream>>>(
            qkv, qkv + D_MODEL, qkv + 2 * D_MODEL, ao,
            3 * D_MODEL, 3 * D_MODEL, D_MODEL,
            (long long)TOK * 3 * D_MODEL, (long long)TOK * 3 * D_MODEL,
            (long long)TOK * D_MODEL, scale);
        gemm_bias_k<<<dim3(16, Mc / 64), 256, 0, stream>>>(
            ao, w_out1, b_out1, ybuf, Mc, D_MODEL, D_MODEL, 0);
        gemm_bias_k<<<dim3(16, Mc / 64), 256, 0, stream>>>(
            ybuf, w_lin, b_lin, Xchunk, Mc, D_MODEL, D_MODEL, 1);

        // ---- Phase 2 scan steps for this chunk ----
        for (int il = 0; il < CHUNK; ++il) {
            int i = w0 + il;
            if (i == 0) continue;          // cum_0 = x[0], consumed at i==1
            const float* cum_src = (i == 1) ? Xchunk : cum;  // x[0] still live
            scan_proj_k<<<dim3(48, 4), 256, 0, stream>>>(
                Xchunk + (size_t)il * WIN_ELEMS, cum_src, w_in2, b_in2, Qb, KVb);
            attn_k<<<dim3(4, NH, 1), 256, 0, stream>>>(
                Qb, KVb, KVb + D_MODEL, AO2,
                D_MODEL, 2 * D_MODEL, D_MODEL, 0, 0, 0, scale);
            float* dst = (i == N_WIN - 1) ? out : cum;
            gemm_bias_k<<<dim3(16, 4), 256, 0, stream>>>(
                AO2, w_out2, b_out2, dst, TOK, D_MODEL, D_MODEL, 0);
        }
    }
}

// Round 3
// 33689.581 us; speedup vs baseline: 2.0026x; 2.0026x over previous
//
#include <hip/hip_runtime.h>
#include <math.h>

// Problem constants
#define D_MODEL 1024
#define N_WIN   240
#define TOK     256
#define NH      16
#define DH      64
#define CHUNK   8
#define NCHUNK  30

typedef unsigned short ushort_t;
typedef __attribute__((ext_vector_type(8))) short short8;
typedef __attribute__((ext_vector_type(4))) float floatx4;

__device__ __forceinline__ float blo(unsigned u) {
    return __uint_as_float(u << 16);
}
__device__ __forceinline__ float bhi(unsigned u) {
    return __uint_as_float(u & 0xffff0000u);
}
__device__ __forceinline__ ushort_t f2bf(float f) {   // RNE, matches torch/jax
    unsigned u = __float_as_uint(f);
    unsigned lsb = (u >> 16) & 1u;
    u += 0x7fffu + lsb;
    return (ushort_t)(u >> 16);
}

// async global->LDS, 16B per lane; LDS dest is wave-uniform base + lane*16
#define GLDS(g, l) __builtin_amdgcn_global_load_lds( \
    (const __attribute__((address_space(1))) unsigned int*)(g), \
    (__attribute__((address_space(3))) unsigned int*)(l), 16, 0, 0)

// ---------------------------------------------------------------------------
// fp32 -> bf16 cast, 4 elems/thread. n must be a multiple of 4.
// ---------------------------------------------------------------------------
__global__ __launch_bounds__(256) void cast_bf_k(
    const float* __restrict__ s, ushort_t* __restrict__ d, int n)
{
    int i = (blockIdx.x * 256 + threadIdx.x) * 4;
    if (i >= n) return;
    float4 v = *(const float4*)(s + i);
    ushort4 o;
    o.x = f2bf(v.x); o.y = f2bf(v.y); o.z = f2bf(v.z); o.w = f2bf(v.w);
    *(ushort4*)(d + i) = o;
}

// ---------------------------------------------------------------------------
// bf16 MFMA GEMM core (m97 structure): C = A @ W^T + bias, optional relu.
// A: [M][lda] bf16 K-major rows. W: [N][K] bf16 (row n = output col n).
// Tile 128x128, BK=32, 4 waves in 2x2, each wave 4x4 of 16x16x32 MFMA.
// Epilogue writes bf16 (Cb) and/or fp32 (Cf), col base `co`, bias index n0+lc.
// GATHER remaps A rows through the sliding-window index (phase-1 QKV).
// ---------------------------------------------------------------------------
template<bool GATHER>
__device__ __forceinline__ void gemm_core(
    const ushort_t* __restrict__ A, int lda, int w0,
    const ushort_t* __restrict__ W, const float* __restrict__ bias,
    ushort_t* __restrict__ Cb, float* __restrict__ Cf, int ldc,
    int K, int m0, int n0, int co, int relu)
{
    __shared__ ushort_t As[128 * 32];   // 8 KB, [row][32] contiguous (no pad!)
    __shared__ ushort_t Bs[128 * 32];
    const int tid = threadIdx.x;
    const int wave = tid >> 6, lane = tid & 63;
    const int wm = wave & 1, wn = wave >> 1;

    int r0 = m0 + (tid >> 2), r1 = r0 + 64;
    if (GATHER) {
        r0 = (w0 + (r0 >> 8)) * 16 + (r0 & 255);
        r1 = (w0 + (r1 >> 8)) * 16 + (r1 & 255);
    }
    const int kcol = (tid & 3) * 8;
    const ushort_t* gA0 = A + (size_t)r0 * lda + kcol;
    const ushort_t* gA1 = A + (size_t)r1 * lda + kcol;
    const ushort_t* pW  = W + (size_t)n0 * K;
    const ushort_t* gB0 = pW + (size_t)(tid >> 2) * K + kcol;
    const ushort_t* gB1 = gB0 + (size_t)64 * K;
    ushort_t* lA = As + wave * 512;     // lane i lands at +i*16B
    ushort_t* lB = Bs + wave * 512;

    floatx4 acc[4][4];
#pragma unroll
    for (int i = 0; i < 4; ++i)
#pragma unroll
        for (int j = 0; j < 4; ++j) acc[i][j] = (floatx4){0.f, 0.f, 0.f, 0.f};

    const int fr = lane & 15, fk = (lane >> 4) * 8;
    const int arow = (wm * 64 + fr) * 32 + fk;   // + mi*512
    const int brow = (wn * 64 + fr) * 32 + fk;   // + ni*512

    for (int k0 = 0; k0 < K; k0 += 32) {
        GLDS(gA0 + k0, lA);
        GLDS(gA1 + k0, lA + 2048);
        GLDS(gB0 + k0, lB);
        GLDS(gB1 + k0, lB + 2048);
        __syncthreads();
        short8 a[4], b[4];
#pragma unroll
        for (int mi = 0; mi < 4; ++mi) a[mi] = *(const short8*)&As[arow + mi * 512];
#pragma unroll
        for (int ni = 0; ni < 4; ++ni) b[ni] = *(const short8*)&Bs[brow + ni * 512];
#pragma unroll
        for (int mi = 0; mi < 4; ++mi)
#pragma unroll
            for (int ni = 0; ni < 4; ++ni)
                acc[mi][ni] = __builtin_amdgcn_mfma_f32_16x16x32_bf16(
                    a[mi], b[ni], acc[mi][ni], 0, 0, 0);
        __syncthreads();
    }

    // C/D layout: col = lane&15, row = (lane>>4)*4 + reg  [verified m89]
    const int crq = (lane >> 4) * 4;
    const int ccol = lane & 15;
#pragma unroll
    for (int mi = 0; mi < 4; ++mi) {
#pragma unroll
        for (int ni = 0; ni < 4; ++ni) {
            int lc = wn * 64 + ni * 16 + ccol;
            float bz = bias[n0 + lc];
#pragma unroll
            for (int rg = 0; rg < 4; ++rg) {
                int row = m0 + wm * 64 + mi * 16 + crq + rg;
                float v = acc[mi][ni][rg] + bz;
                if (relu) v = fmaxf(v, 0.f);
                size_t off = (size_t)row * ldc + co + lc;
                if (Cb) Cb[off] = f2bf(v);
                if (Cf) Cf[off] = v;
            }
        }
    }
}

__global__ __launch_bounds__(256) void gemm_bf_k(
    const ushort_t* __restrict__ A, int lda,
    const ushort_t* __restrict__ W, const float* __restrict__ bias,
    ushort_t* __restrict__ Cb, float* __restrict__ Cf, int ldc,
    int K, int relu)
{
    gemm_core<false>(A, lda, 0, W, bias, Cb, Cf, ldc, K,
                     blockIdx.y * 128, blockIdx.x * 128, blockIdx.x * 128, relu);
}

__global__ __launch_bounds__(256) void gemm_qkv_k(
    const ushort_t* __restrict__ path_bf, const ushort_t* __restrict__ W,
    const float* __restrict__ bias, ushort_t* __restrict__ Cb, int w0)
{
    gemm_core<true>(path_bf, 1024, w0, W, bias, Cb, nullptr, 3072, 1024,
                    blockIdx.y * 128, blockIdx.x * 128, blockIdx.x * 128, 0);
}

// scan projection: n0<1024 -> Q = Xi @ wq^T ; else KV = cum @ wkv^T
__global__ __launch_bounds__(256) void scan_proj_k(
    const ushort_t* __restrict__ Xi, const ushort_t* __restrict__ cum,
    const ushort_t* __restrict__ W, const float* __restrict__ bias,
    ushort_t* __restrict__ Qb, ushort_t* __restrict__ KVb)
{
    int n0 = blockIdx.x * 128, m0 = blockIdx.y * 128;
    if (n0 < 1024)
        gemm_core<false>(Xi, 1024, 0, W, bias, Qb, nullptr, 1024, 1024,
                         m0, n0, n0, 0);
    else
        gemm_core<false>(cum, 1024, 0, W, bias, KVb, nullptr, 2048, 1024,
                         m0, n0, n0 - 1024, 0);
}

// ---------------------------------------------------------------------------
// MHA core (L=256 keys, Dh=64), bf16 in/out, fp32 math, online softmax.
// Grid: (row_slice 0..3, head, batch). Block 256 = 64 rows x 4 waves;
// wave s covers key slice [s*64, s*64+64) -> LDS merge.
// ---------------------------------------------------------------------------
__global__ __launch_bounds__(256) void attn_k(
    const ushort_t* __restrict__ Q, const ushort_t* __restrict__ Kp,
    const ushort_t* __restrict__ Vp, ushort_t* __restrict__ O,
    int ldq, int ldk, int ldo,
    long long qBatch, long long kBatch, long long oBatch, float scale)
{
    const int h = blockIdx.y;
    const long long b = blockIdx.z;
    const ushort_t* qb = Q  + b * qBatch + h * DH;
    const ushort_t* kb = Kp + b * kBatch + h * DH;
    const ushort_t* vb = Vp + b * kBatch + h * DH;
    const int tid = threadIdx.x;
    const int rr = tid & 63;
    const int s  = tid >> 6;
    const int r  = (blockIdx.x << 6) + rr;

    float qr[64];
    {
        const uint4* qrow = (const uint4*)(qb + (size_t)r * ldq);
#pragma unroll
        for (int c = 0; c < 8; ++c) {
            uint4 p = qrow[c];
            qr[c * 8 + 0] = blo(p.x); qr[c * 8 + 1] = bhi(p.x);
            qr[c * 8 + 2] = blo(p.y); qr[c * 8 + 3] = bhi(p.y);
            qr[c * 8 + 4] = blo(p.z); qr[c * 8 + 5] = bhi(p.z);
            qr[c * 8 + 6] = blo(p.w); qr[c * 8 + 7] = bhi(p.w);
        }
    }

    float m = -INFINITY, l = 0.f;
    float o[64];
#pragma unroll
    for (int i = 0; i < 64; ++i) o[i] = 0.f;

    const int j0 = s << 6;
    for (int j = j0; j < j0 + 64; ++j) {
        const uint4* krow = (const uint4*)(kb + (size_t)j * ldk);
        float dot = 0.f;
#pragma unroll
        for (int c = 0; c < 8; ++c) {
            uint4 p = krow[c];
            dot = fmaf(qr[c * 8 + 0], blo(p.x), dot);
            dot = fmaf(qr[c * 8 + 1], bhi(p.x), dot);
            dot = fmaf(qr[c * 8 + 2], blo(p.y), dot);
            dot = fmaf(qr[c * 8 + 3], bhi(p.y), dot);
            dot = fmaf(qr[c * 8 + 4], blo(p.z), dot);
            dot = fmaf(qr[c * 8 + 5], bhi(p.z), dot);
            dot = fmaf(qr[c * 8 + 6], blo(p.w), dot);
            dot = fmaf(qr[c * 8 + 7], bhi(p.w), dot);
        }
        float sc = dot * scale;
        float mn = fmaxf(m, sc);
        float alpha = __expf(m - mn);
        float p = __expf(sc - mn);
        l = l * alpha + p;
        m = mn;
        const uint4* vrow = (const uint4*)(vb + (size_t)j * ldk);
#pragma unroll
        for (int c = 0; c < 8; ++c) {
            uint4 pv = vrow[c];
            o[c * 8 + 0] = fmaf(p, blo(pv.x), o[c * 8 + 0] * alpha);
            o[c * 8 + 1] = fmaf(p, bhi(pv.x), o[c * 8 + 1] * alpha);
            o[c * 8 + 2] = fmaf(p, blo(pv.y), o[c * 8 + 2] * alpha);
            o[c * 8 + 3] = fmaf(p, bhi(pv.y), o[c * 8 + 3] * alpha);
            o[c * 8 + 4] = fmaf(p, blo(pv.z), o[c * 8 + 4] * alpha);
            o[c * 8 + 5] = fmaf(p, bhi(pv.z), o[c * 8 + 5] * alpha);
            o[c * 8 + 6] = fmaf(p, blo(pv.w), o[c * 8 + 6] * alpha);
            o[c * 8 + 7] = fmaf(p, bhi(pv.w), o[c * 8 + 7] * alpha);
        }
    }

    __shared__ float sm[4][64];
    __shared__ float sl[4][64];
    __shared__ float Oa[64][68];
    sm[s][rr] = m;
    sl[s][rr] = l;
    __syncthreads();
    float M2 = fmaxf(fmaxf(sm[0][rr], sm[1][rr]), fmaxf(sm[2][rr], sm[3][rr]));
    float L = 0.f;
#pragma unroll
    for (int s2 = 0; s2 < 4; ++s2) L += sl[s2][rr] * __expf(sm[s2][rr] - M2);
    float myw = __expf(m - M2);
#pragma unroll
    for (int i = 0; i < 64; ++i) o[i] *= myw;
#pragma unroll
    for (int p = 0; p < 4; ++p) {
        if (s == p) {
            if (p == 0) {
#pragma unroll
                for (int i = 0; i < 64; ++i) Oa[rr][i] = o[i];
            } else {
#pragma unroll
                for (int i = 0; i < 64; ++i) Oa[rr][i] += o[i];
            }
        }
        __syncthreads();
    }
    float invL = 1.f / L;
    ushort_t* orow = O + b * oBatch + h * DH + (size_t)r * ldo;
#pragma unroll
    for (int i = 0; i < 4; ++i) {
        int d = (s << 4) + (i << 2);
        ushort4 res;
        res.x = f2bf(Oa[rr][d + 0] * invL);
        res.y = f2bf(Oa[rr][d + 1] * invL);
        res.z = f2bf(Oa[rr][d + 2] * invL);
        res.w = f2bf(Oa[rr][d + 3] * invL);
        *(ushort4*)(orow + d) = res;
    }
}

// ---------------------------------------------------------------------------
extern "C" void kernel_launch(void* const* d_in, const int* in_sizes, int n_in,
                              void* d_out, int out_size, void* d_ws, size_t ws_size,
                              hipStream_t stream)
{
    const float* path   = (const float*)d_in[0];
    const float* w_in1  = (const float*)d_in[1];
    const float* b_in1  = (const float*)d_in[2];
    const float* w_out1 = (const float*)d_in[3];
    const float* b_out1 = (const float*)d_in[4];
    const float* w_lin  = (const float*)d_in[5];
    const float* b_lin  = (const float*)d_in[6];
    const float* w_in2  = (const float*)d_in[7];
    const float* b_in2  = (const float*)d_in[8];
    const float* w_out2 = (const float*)d_in[9];
    const float* b_out2 = (const float*)d_in[10];
    float* out = (float*)d_out;

    // workspace (bf16 elems) — total ~52.5 MB
    ushort_t* ws = (ushort_t*)d_ws;
    const size_t WIN = (size_t)TOK * D_MODEL;            // 262144
    ushort_t* path_bf  = ws;                              // 4096*1024
    ushort_t* w_in1_bf = path_bf  + (size_t)4096 * 1024;  // 3072*1024
    ushort_t* w_out1_bf= w_in1_bf + (size_t)3072 * 1024;  // 1024*1024
    ushort_t* w_lin_bf = w_out1_bf+ (size_t)1024 * 1024;
    ushort_t* w_in2_bf = w_lin_bf + (size_t)1024 * 1024;  // 3072*1024
    ushort_t* w_out2_bf= w_in2_bf + (size_t)3072 * 1024;
    ushort_t* qkv_bf   = w_out2_bf+ (size_t)1024 * 1024;  // 2048*3072
    ushort_t* ao_bf    = qkv_bf   + (size_t)2048 * 3072;  // 2048*1024
    ushort_t* ybuf_bf  = ao_bf    + (size_t)2048 * 1024;
    ushort_t* Xchunk   = ybuf_bf  + (size_t)2048 * 1024;  // 2048*1024
    ushort_t* Qb       = Xchunk   + (size_t)2048 * 1024;  // 256*1024
    ushort_t* KVb      = Qb  + WIN;                       // 256*2048
    ushort_t* AO2      = KVb + 2 * WIN;                   // 256*1024
    ushort_t* cum      = AO2 + WIN;                       // 256*1024

    const float scale = 0.125f;

    // ---- casts (weights + path), once per call ----
    cast_bf_k<<<4096, 256, 0, stream>>>(path,  path_bf,  4096 * 1024);
    cast_bf_k<<<3072, 256, 0, stream>>>(w_in1, w_in1_bf, 3072 * 1024);
    cast_bf_k<<<1024, 256, 0, stream>>>(w_out1, w_out1_bf, 1024 * 1024);
    cast_bf_k<<<1024, 256, 0, stream>>>(w_lin, w_lin_bf, 1024 * 1024);
    cast_bf_k<<<3072, 256, 0, stream>>>(w_in2, w_in2_bf, 3072 * 1024);
    cast_bf_k<<<1024, 256, 0, stream>>>(w_out2, w_out2_bf, 1024 * 1024);

    for (int c = 0; c < NCHUNK; ++c) {
        int w0 = c * CHUNK;
        // ---- Phase 1 for windows [w0, w0+CHUNK) ----
        gemm_qkv_k<<<dim3(24, 16), 256, 0, stream>>>(
            path_bf, w_in1_bf, b_in1, qkv_bf, w0);
        attn_k<<<dim3(4, NH, CHUNK), 256, 0, stream>>>(
            qkv_bf, qkv_bf + 1024, qkv_bf + 2048, ao_bf,
            3072, 3072, 1024,
            (long long)TOK * 3072, (long long)TOK * 3072,
            (long long)TOK * 1024, scale);
        gemm_bf_k<<<dim3(8, 16), 256, 0, stream>>>(
            ao_bf, 1024, w_out1_bf, b_out1, ybuf_bf, nullptr, 1024, 1024, 0);
        gemm_bf_k<<<dim3(8, 16), 256, 0, stream>>>(
            ybuf_bf, 1024, w_lin_bf, b_lin, Xchunk, nullptr, 1024, 1024, 1);

        // ---- Phase 2 scan steps for this chunk ----
        for (int il = 0; il < CHUNK; ++il) {
            int i = w0 + il;
            if (i == 0) continue;
            const ushort_t* cum_src = (i == 1) ? Xchunk : cum;  // x[0] live
            scan_proj_k<<<dim3(24, 2), 256, 0, stream>>>(
                Xchunk + (size_t)il * WIN, cum_src, w_in2_bf, b_in2, Qb, KVb);
            attn_k<<<dim3(4, NH, 1), 256, 0, stream>>>(
                Qb, KVb, KVb + 1024, AO2,
                1024, 2048, 1024, 0, 0, 0, scale);
            float* cf = (i == N_WIN - 1) ? out : nullptr;
            gemm_bf_k<<<dim3(8, 2), 256, 0, stream>>>(
                AO2, 1024, w_out2_bf, b_out2, cum, cf, 1024, 1024, 0);
        }
    }
}